// Round 6
// baseline (167.655 us; speedup 1.0000x reference)
//
#include <hip/hip_runtime.h>
#include <math.h>

#define NCLS 80
#define TOPK 1000
#define NWORDS 16          // ceil(1000/64)
#define CAND_CAP 4096

// Correctly-rounded float sigmoid: matches numpy's 1/(1+np.exp(-x)) bit-for-bit.
__device__ __forceinline__ float sigmoid_np(float x) {
  float e = (float)exp(-(double)x);
  return 1.0f / (1.0f + e);
}
__device__ __forceinline__ float exp_np(float x) { return (float)exp((double)x); }

// monotonic float->uint key
__device__ __forceinline__ unsigned fkey(float s) {
  unsigned u = __float_as_uint(s);
  return ((int)u < 0) ? ~u : (u | 0x80000000u);
}

// Wave-aggregated LDS histogram add: one atomic per distinct bin per wave.
__device__ __forceinline__ void agg_add(unsigned* h, unsigned bin, bool pred) {
  unsigned long long rem = __ballot(pred);
  const int lane = threadIdx.x & 63;
  while (rem) {
    int leader = __ffsll(rem) - 1;
    unsigned lb = (unsigned)__shfl((int)bin, leader, 64);
    unsigned long long m = __ballot(pred && bin == lb);
    if (lane == leader) atomicAdd(&h[lb], (unsigned)__popcll(m));
    rem &= ~m;
  }
}

// 4 lanes per anchor; argmax on raw logits; one exact sigmoid per anchor;
// fused per-block LDS histogram of key[31:20] merged to ghist1 (nonzero bins only).
__launch_bounds__(1024)
__global__ void k_score(const float* __restrict__ cls, float* __restrict__ scores,
                        int* __restrict__ labels, unsigned* __restrict__ ghist1, int M) {
  __shared__ unsigned h1[4096];
  const int t = threadIdx.x;
  #pragma unroll
  for (int k = 0; k < 4; ++k) h1[t + 1024 * k] = 0u;
  __syncthreads();

  int gid = blockIdx.x * 1024 + t;
  int anchor = gid >> 2;
  int q = gid & 3;
  bool act = anchor < M;
  float lv[20];
  float best = -3.4e38f; int bc = 0;
  if (act) {
    const float4* row = reinterpret_cast<const float4*>(cls) + (size_t)anchor * (NCLS / 4);
    #pragma unroll
    for (int k = 0; k < 5; ++k) {
      float4 v = row[q + 4 * k];
      int cbase = (q + 4 * k) * 4;
      lv[4 * k + 0] = v.x; lv[4 * k + 1] = v.y; lv[4 * k + 2] = v.z; lv[4 * k + 3] = v.w;
      if (v.x > best) { best = v.x; bc = cbase + 0; }
      if (v.y > best) { best = v.y; bc = cbase + 1; }
      if (v.z > best) { best = v.z; bc = cbase + 2; }
      if (v.w > best) { best = v.w; bc = cbase + 3; }
    }
  } else {
    #pragma unroll
    for (int k = 0; k < 20; ++k) lv[k] = -3.4e38f;
  }
  #pragma unroll
  for (int d = 1; d < 4; d <<= 1) {
    float ob = __shfl_xor(best, d, 64);
    int oc = __shfl_xor(bc, d, 64);
    if (ob > best || (ob == best && oc < bc)) { best = ob; bc = oc; }
  }
  float s = sigmoid_np(best);
  // collision band: logit gap below this can round to the same float sigmoid
  float sp = s * (1.0f - s);
  float band = (s < 1.0f && sp > 0.0f) ? (4.8e-7f / sp) : 3.4e38f;  // 8 ulps margin
  float thresh = best - band;
  int cclose = 1 << 30;
  #pragma unroll
  for (int k = 0; k < 5; ++k) {
    #pragma unroll
    for (int j = 0; j < 4; ++j) {
      int c = (q + 4 * k) * 4 + j;
      if (lv[4 * k + j] >= thresh && c < cclose) cclose = c;
    }
  }
  #pragma unroll
  for (int d = 1; d < 4; d <<= 1) {
    int oc = __shfl_xor(cclose, d, 64);
    if (oc < cclose) cclose = oc;
  }
  int lab = bc;
  if (act && cclose < bc && q == 0) {  // rare: exact serial argmax over rounded sigmoids
    float bp = -1.0f; int bl = 0;
    for (int c = 0; c < NCLS; ++c) {
      float p = sigmoid_np(cls[(size_t)anchor * NCLS + c]);
      if (p > bp) { bp = p; bl = c; }
    }
    lab = bl;
  }
  if (act && q == 0) {
    scores[anchor] = s;
    labels[anchor] = lab;
  }
  agg_add(h1, fkey(s) >> 20, act && q == 0);
  __syncthreads();
  #pragma unroll
  for (int k = 0; k < 4; ++k) {
    unsigned c = h1[t + 1024 * k];
    if (c) atomicAdd(&ghist1[t + 1024 * k], c);
  }
}

// Each block recomputes B1 (coarse threshold bin) from ghist1, then histograms
// key bits [19:8] of elements in bin B1 into global ghist2. Block 0 stores meta.
__launch_bounds__(1024)
__global__ void k_hist2(const unsigned* __restrict__ ghist1, const float* __restrict__ scores,
                        unsigned* __restrict__ ghist2, unsigned* __restrict__ gmeta, int M) {
  __shared__ unsigned chunks[1024];
  __shared__ int sB1; __shared__ unsigned sAb;
  const int t = threadIdx.x;
  unsigned hb0 = ghist1[4 * t], hb1 = ghist1[4 * t + 1],
           hb2 = ghist1[4 * t + 2], hb3 = ghist1[4 * t + 3];
  chunks[t] = hb0 + hb1 + hb2 + hb3;
  __syncthreads();
  for (int d = 1; d < 1024; d <<= 1) {   // inclusive suffix sum
    unsigned v = chunks[t] + ((t + d < 1024) ? chunks[t + d] : 0u);
    __syncthreads();
    chunks[t] = v;
    __syncthreads();
  }
  {
    unsigned ssc = chunks[t];
    unsigned ssn = (t + 1 < 1024) ? chunks[t + 1] : 0u;
    if (ssc >= (unsigned)TOPK && ssn < (unsigned)TOPK) {
      unsigned hb[4] = {hb0, hb1, hb2, hb3};
      unsigned run = ssn;
      for (int b = 3; b >= 0; --b) {
        run += hb[b];
        if (run >= (unsigned)TOPK) { sB1 = 4 * t + b; sAb = run - hb[b]; break; }
      }
    }
  }
  __syncthreads();
  const unsigned B1 = (unsigned)sB1;
  if (blockIdx.x == 0 && t == 0) { gmeta[0] = B1; gmeta[1] = sAb; }

  int base = (blockIdx.x * 1024 + t) * 4;
  if (base + 3 < M) {
    float4 v = *reinterpret_cast<const float4*>(scores + base);
    unsigned k0 = fkey(v.x), k1 = fkey(v.y), k2 = fkey(v.z), k3 = fkey(v.w);
    if ((k0 >> 20) == B1) atomicAdd(&ghist2[(k0 >> 8) & 0xFFFu], 1u);
    if ((k1 >> 20) == B1) atomicAdd(&ghist2[(k1 >> 8) & 0xFFFu], 1u);
    if ((k2 >> 20) == B1) atomicAdd(&ghist2[(k2 >> 8) & 0xFFFu], 1u);
    if ((k3 >> 20) == B1) atomicAdd(&ghist2[(k3 >> 8) & 0xFFFu], 1u);
  } else {
    for (int j = base; j < M; ++j) {
      unsigned k0 = fkey(scores[j]);
      if ((k0 >> 20) == B1) atomicAdd(&ghist2[(k0 >> 8) & 0xFFFu], 1u);
    }
  }
}

// Each block recomputes the 24-bit threshold T from ghist2+meta, then compacts
// its slice of keys >= T into the global candidate buffer (1 atomic per block).
__launch_bounds__(1024)
__global__ void k_compact(const unsigned* __restrict__ ghist2, const unsigned* __restrict__ gmeta,
                          const float* __restrict__ scores,
                          unsigned long long* __restrict__ cand, unsigned* __restrict__ gcount,
                          int M) {
  __shared__ unsigned chunks[1024];
  __shared__ int sB2;
  __shared__ unsigned wcnt[16];
  __shared__ unsigned sbase;
  const int t = threadIdx.x;
  const unsigned B1 = gmeta[0], nAb = gmeta[1];
  unsigned hb0 = ghist2[4 * t], hb1 = ghist2[4 * t + 1],
           hb2 = ghist2[4 * t + 2], hb3 = ghist2[4 * t + 3];
  chunks[t] = hb0 + hb1 + hb2 + hb3;
  __syncthreads();
  for (int d = 1; d < 1024; d <<= 1) {
    unsigned v = chunks[t] + ((t + d < 1024) ? chunks[t + d] : 0u);
    __syncthreads();
    chunks[t] = v;
    __syncthreads();
  }
  {
    unsigned ssc = nAb + chunks[t];
    unsigned ssn = nAb + ((t + 1 < 1024) ? chunks[t + 1] : 0u);
    if (ssc >= (unsigned)TOPK && ssn < (unsigned)TOPK) {
      unsigned hb[4] = {hb0, hb1, hb2, hb3};
      unsigned run = ssn;
      for (int b = 3; b >= 0; --b) {
        run += hb[b];
        if (run >= (unsigned)TOPK) { sB2 = 4 * t + b; break; }
      }
    }
  }
  __syncthreads();
  const unsigned T = (B1 << 20) | ((unsigned)sB2 << 8);

  int base = (blockIdx.x * 1024 + t) * 4;
  unsigned keys[4]; int idxs[4]; int np = 0;
  #pragma unroll
  for (int j = 0; j < 4; ++j) {
    int i = base + j;
    if (i < M) {
      unsigned key = fkey(scores[i]);
      if (key >= T) { keys[np] = key; idxs[np] = i; ++np; }
    }
  }
  // wave inclusive scan of np
  const int lane = t & 63, wid = t >> 6;
  int sc = np;
  #pragma unroll
  for (int d = 1; d < 64; d <<= 1) {
    int o = __shfl_up(sc, d, 64);
    if (lane >= d) sc += o;
  }
  if (lane == 63) wcnt[wid] = (unsigned)sc;
  __syncthreads();
  if (t == 0) {
    unsigned acc = 0;
    for (int w = 0; w < 16; ++w) { unsigned v = wcnt[w]; wcnt[w] = acc; acc += v; }
    sbase = acc ? atomicAdd(gcount, acc) : 0u;
  }
  __syncthreads();
  unsigned pos = sbase + wcnt[wid] + (unsigned)(sc - np);
  for (int j = 0; j < np; ++j) {
    if (pos < (unsigned)CAND_CAP)
      cand[pos] = ((unsigned long long)keys[j] << 32) | (unsigned)(~(unsigned)idxs[j]);
    ++pos;
  }
}

// Exact rank (N^2 over <=CAND_CAP distinct keys) + decode, one block.
__launch_bounds__(1024)
__global__ void k_rank(const unsigned long long* __restrict__ cand, const unsigned* __restrict__ gcount,
                       const int* __restrict__ labels, const float* __restrict__ reg,
                       const float* __restrict__ asz, const int* __restrict__ pW, int A,
                       float* __restrict__ sel_score, int* __restrict__ sel_label,
                       float* __restrict__ boxes, float* __restrict__ areas,
                       float* __restrict__ obox) {
  __shared__ unsigned long long ck[CAND_CAP];  // 32KB
  const int t = threadIdx.x;
  unsigned n = *gcount; if (n > (unsigned)CAND_CAP) n = (unsigned)CAND_CAP;
  for (int i = t; i < CAND_CAP; i += 1024) ck[i] = (i < (int)n) ? cand[i] : 0ull;
  __syncthreads();
  for (int c = t; c < (int)n; c += 1024) {
    unsigned long long my = ck[c];
    int r = 0;
    for (int j = 0; j < (int)n; ++j) r += (ck[j] > my);   // uniform j: LDS broadcast
    if (r < TOPK) {
      unsigned key = (unsigned)(my >> 32);
      unsigned u = (key & 0x80000000u) ? (key ^ 0x80000000u) : ~key;
      float scv = __uint_as_float(u);
      int idx = (int)(~(unsigned)my);
      int lab = labels[idx];
      int W = *pW;
      int a = idx % A;
      int cell = idx / A;
      int x = cell % W;
      int y = cell / W;
      float aw = asz[a * 2 + 0], ah = asz[a * 2 + 1];
      float ax = ((float)x + 0.5f) * 32.0f;
      float ay = ((float)y + 0.5f) * 32.0f;
      float4 rg = *reinterpret_cast<const float4*>(reg + (size_t)idx * 4);
      float offx = fminf(fmaxf(rg.x * aw, -32.0f), 32.0f);
      float offy = fminf(fmaxf(rg.y * ah, -32.0f), 32.0f);
      float cx = ax + offx, cy = ay + offy;
      const float SC = 4.135166556742356f;  // log(1000/16)
      float bw = aw * exp_np(fminf(rg.z, SC));
      float bh = ah * exp_np(fminf(rg.w, SC));
      float x1 = cx - 0.5f * bw, y1 = cy - 0.5f * bh;
      float x2 = cx + 0.5f * bw, y2 = cy + 0.5f * bh;
      float off = (float)lab * 100000.0f;
      float ox1 = x1 + off, oy1 = y1 + off, ox2 = x2 + off, oy2 = y2 + off;
      sel_score[r] = scv; sel_label[r] = lab;
      boxes[r * 4 + 0] = x1; boxes[r * 4 + 1] = y1;
      boxes[r * 4 + 2] = x2; boxes[r * 4 + 3] = y2;
      obox[0 * 1024 + r] = ox1; obox[1 * 1024 + r] = oy1;
      obox[2 * 1024 + r] = ox2; obox[3 * 1024 + r] = oy2;
      areas[r] = (ox2 - ox1) * (oy2 - oy1);  // areas on offset boxes, like the reference
    }
  }
}

// Block-uniform word index wq; boxes staged in LDS (same-address broadcast reads).
// Mask stored TRANSPOSED: maskT[wq*1024 + i].
__launch_bounds__(256)
__global__ void k_mask(const float* __restrict__ obox, const float* __restrict__ areas,
                       unsigned long long* __restrict__ maskT) {
  __shared__ float so0[1024], so1[1024], so2[1024], so3[1024], sa[1024];
  const int t = threadIdx.x;
  int g = blockIdx.x * 256 + t;
  int wq = g >> 10, i = g & 1023;
  for (int idx = t; idx < 1024; idx += 256) {
    so0[idx] = obox[idx];        so1[idx] = obox[1024 + idx];
    so2[idx] = obox[2048 + idx]; so3[idx] = obox[3072 + idx];
    sa[idx] = areas[idx];
  }
  __syncthreads();
  if (i >= TOPK) return;
  float x1i = so0[i], y1i = so1[i], x2i = so2[i], y2i = so3[i];
  float ai = sa[i];
  unsigned long long bits = 0ull;
  int j0 = wq * 64;
  for (int jj = 0; jj < 64; ++jj) {
    int j = j0 + jj;                       // block-uniform: LDS broadcast
    if (j < TOPK && j > i) {
      float xx1 = fmaxf(x1i, so0[j]);
      float yy1 = fmaxf(y1i, so1[j]);
      float xx2 = fminf(x2i, so2[j]);
      float yy2 = fminf(y2i, so3[j]);
      float inter = fmaxf(1e-28f, xx2 - xx1) * fmaxf(1e-28f, yy2 - yy1);
      float uni = ai + sa[j] - inter + 1e-14f;
      float iou = inter / uni;             // IEEE division: bit-matches reference
      if (iou > 0.6f) bits |= (1ull << jj);
    }
  }
  maskT[wq * 1024 + i] = bits;
}

__device__ __forceinline__ unsigned long long shfl64(unsigned long long v, int src) {
  unsigned lo = (unsigned)__shfl((int)(unsigned)(v & 0xffffffffull), src, 64);
  unsigned hi = (unsigned)__shfl((int)(unsigned)(v >> 32), src, 64);
  return ((unsigned long long)hi << 32) | lo;
}

// SINGLE-WAVE serial greedy NMS + fused output epilogue.
// __launch_bounds__(64, 1): 1 wave/EU minimum -> full 512-VGPR budget so the
// ping-pong prefetch sets (4 x 8 x u64 = 64 VGPR) stay in registers. Manual
// two-set ping-pong (named arrays, static indices only) -- no copy rotation,
// no dynamic buffer select (rule #20).
#define NMS_LOADG(A, W, g)                                                  \
  do {                                                                      \
    _Pragma("unroll")                                                       \
    for (int k = 0; k < 8; ++k) {                                           \
      int i_ = (g) * 8 + k;                                                 \
      W[k] = mT[(i_ >> 6) * 1025 + i_];        /* same-addr broadcast */    \
      A[k] = ln ? mT[lane * 1025 + i_] : 0ull; /* per-lane word */          \
    }                                                                       \
  } while (0)

#define NMS_STEPG(A, W, g)                                                  \
  do {                                                                      \
    _Pragma("unroll")                                                       \
    for (int k = 0; k < 8; ++k) {                                           \
      int i_ = (g) * 8 + k;                                                 \
      int wi_ = i_ >> 6, bit_ = i_ & 63;                                    \
      if (bit_ == 0) {                                                      \
        unsigned long long cs_ = shfl64(supp, wi_);                         \
        unsigned long long cv_ = shfl64(vl, wi_);                           \
        avail = cv_ & ~cs_;                                                 \
      }                                                                     \
      if ((avail >> bit_) & 1ull) {                                         \
        avail &= ~W[k];                 /* register-local chain */          \
        supp |= A[k];                   /* distributed OR, lanes 0..15 */   \
        if (lane == wi_) kw |= (1ull << bit_);                              \
      }                                                                     \
    }                                                                       \
  } while (0)

__launch_bounds__(64, 1)
__global__ void k_nms(const unsigned long long* __restrict__ maskT,
                      const float* __restrict__ sel_score, const int* __restrict__ sel_label,
                      const float* __restrict__ boxes,
                      const int* __restrict__ pW, const int* __restrict__ pH,
                      float* __restrict__ out) {
  __shared__ unsigned long long mT[NWORDS * 1025];  // padded: stride 1025
  const int lane = threadIdx.x;
  const ulonglong2* m2 = reinterpret_cast<const ulonglong2*>(maskT);
  for (int idx = lane; idx < NWORDS * 512; idx += 64) {
    ulonglong2 v = m2[idx];
    int w = idx >> 9;
    int p = (idx & 511) * 2;
    mT[w * 1025 + p] = v.x;
    mT[w * 1025 + p + 1] = v.y;
  }
  unsigned long long vl = 0ull;   // lane i (i<16) holds valid word i
  #pragma unroll
  for (int i = 0; i < NWORDS; ++i) {
    int r = i * 64 + lane;
    bool ok = (r < TOPK) && (sel_score[r] >= 0.05f);
    unsigned long long b = __ballot(ok);
    if (lane == i) vl = b;
  }
  __syncthreads();

  const bool ln = lane < NWORDS;
  unsigned long long supp = 0ull, kw = 0ull, avail = 0ull;
  unsigned long long A0[8], W0[8], A1[8], W1[8];
  // 128 groups x 8 rows = all 1024 rows; rows >= TOPK are masked by vl bits=0.
  NMS_LOADG(A0, W0, 0);
  for (int g = 0; g < 128; g += 2) {
    NMS_LOADG(A1, W1, g + 1);
    NMS_STEPG(A0, W0, g);
    if (g + 2 < 128) NMS_LOADG(A0, W0, g + 2);
    NMS_STEPG(A1, W1, g + 1);
  }

  // Fused output epilogue (single wave, 16 iterations of 64 rows).
  float sw = (float)(*pW * 32);
  float sh = (float)(*pH * 32);
  const float4* b4 = reinterpret_cast<const float4*>(boxes);
  #pragma unroll
  for (int it = 0; it < 16; ++it) {
    int r = it * 64 + lane;
    unsigned long long kword = shfl64(kw, it);   // keep-word for rows [it*64, it*64+64)
    if (r < TOPK) {
      bool kp = (kword >> lane) & 1ull;
      float m = kp ? 1.0f : 0.0f;
      float4 b = b4[r];
      float b0 = fminf(fmaxf(b.x / sw, 0.0f), 1.0f) * m;
      float b1 = fminf(fmaxf(b.y / sh, 0.0f), 1.0f) * m;
      float b2 = fminf(fmaxf(b.z / sw, 0.0f), 1.0f) * m;
      float b3 = fminf(fmaxf(b.w / sh, 0.0f), 1.0f) * m;
      out[r * 4 + 0] = b0; out[r * 4 + 1] = b1;
      out[r * 4 + 2] = b2; out[r * 4 + 3] = b3;
      out[TOPK * 4 + r] = sel_score[r] * m;
      out[TOPK * 5 + r] = kp ? (float)sel_label[r] : -1.0f;
      out[TOPK * 6 + r] = m;
    }
  }
}

extern "C" void kernel_launch(void* const* d_in, const int* in_sizes, int n_in,
                              void* d_out, int out_size, void* d_ws, size_t ws_size,
                              hipStream_t stream) {
  const float* cls = (const float*)d_in[0];
  const float* reg = (const float*)d_in[1];
  const float* asz = (const float*)d_in[2];
  const int* pH = (const int*)d_in[3];
  const int* pW = (const int*)d_in[4];
  int M = in_sizes[0] / NCLS;
  int A = in_sizes[2] / 2;

  char* ws = (char*)d_ws;
  size_t off = 0;
  auto alloc = [&](size_t bytes) { size_t o = off; off = (off + bytes + 255) & ~(size_t)255; return o; };
  size_t o_h1    = alloc(4096 * sizeof(unsigned));
  size_t o_h2    = alloc(4096 * sizeof(unsigned));
  size_t o_misc  = alloc(256);                       // gcount @ +0, gmeta @ +8
  size_t zero_end = off;
  size_t o_cand  = alloc((size_t)CAND_CAP * sizeof(unsigned long long));
  size_t o_sc    = alloc((size_t)M * sizeof(float));
  size_t o_lb    = alloc((size_t)M * sizeof(int));
  size_t o_ssc   = alloc(1024 * sizeof(float));
  size_t o_slb   = alloc(1024 * sizeof(int));
  size_t o_box   = alloc((size_t)TOPK * 4 * sizeof(float));
  size_t o_area  = alloc(1024 * sizeof(float));
  size_t o_obox  = alloc(4 * 1024 * sizeof(float));
  size_t o_mask  = alloc((size_t)NWORDS * 1024 * sizeof(unsigned long long));
  (void)ws_size; (void)out_size; (void)n_in;

  hipMemsetAsync(ws, 0, zero_end, stream);   // ghist1 + ghist2 + gcount/gmeta

  int nblk_score = (M * 4 + 1023) / 1024;
  k_score<<<nblk_score, 1024, 0, stream>>>(
      cls, (float*)(ws + o_sc), (int*)(ws + o_lb), (unsigned*)(ws + o_h1), M);

  int nblk_scan = ((M + 3) / 4 + 1023) / 1024;
  k_hist2<<<nblk_scan, 1024, 0, stream>>>(
      (const unsigned*)(ws + o_h1), (const float*)(ws + o_sc),
      (unsigned*)(ws + o_h2), (unsigned*)(ws + o_misc + 8), M);
  k_compact<<<nblk_scan, 1024, 0, stream>>>(
      (const unsigned*)(ws + o_h2), (const unsigned*)(ws + o_misc + 8),
      (const float*)(ws + o_sc),
      (unsigned long long*)(ws + o_cand), (unsigned*)(ws + o_misc), M);
  k_rank<<<1, 1024, 0, stream>>>(
      (const unsigned long long*)(ws + o_cand), (const unsigned*)(ws + o_misc),
      (const int*)(ws + o_lb), reg, asz, pW, A,
      (float*)(ws + o_ssc), (int*)(ws + o_slb),
      (float*)(ws + o_box), (float*)(ws + o_area), (float*)(ws + o_obox));
  k_mask<<<(NWORDS * 1024) / 256, 256, 0, stream>>>(
      (const float*)(ws + o_obox), (const float*)(ws + o_area),
      (unsigned long long*)(ws + o_mask));
  k_nms<<<1, 64, 0, stream>>>(
      (const unsigned long long*)(ws + o_mask),
      (const float*)(ws + o_ssc), (const int*)(ws + o_slb),
      (const float*)(ws + o_box), pW, pH, (float*)d_out);
}

// Round 7
// 112.208 us; speedup vs baseline: 1.4941x; 1.4941x over previous
//
#include <hip/hip_runtime.h>
#include <math.h>

#define NCLS 80
#define TOPK 1000
#define NWORDS 16          // ceil(1000/64)
#define CAND_CAP 4096

// Correctly-rounded float sigmoid: matches numpy's 1/(1+np.exp(-x)) bit-for-bit.
__device__ __forceinline__ float sigmoid_np(float x) {
  float e = (float)exp(-(double)x);
  return 1.0f / (1.0f + e);
}
__device__ __forceinline__ float exp_np(float x) { return (float)exp((double)x); }

// monotonic float->uint key
__device__ __forceinline__ unsigned fkey(float s) {
  unsigned u = __float_as_uint(s);
  return ((int)u < 0) ? ~u : (u | 0x80000000u);
}

// Wave-aggregated LDS histogram add: one atomic per distinct bin per wave.
__device__ __forceinline__ void agg_add(unsigned* h, unsigned bin, bool pred) {
  unsigned long long rem = __ballot(pred);
  const int lane = threadIdx.x & 63;
  while (rem) {
    int leader = __ffsll(rem) - 1;
    unsigned lb = (unsigned)__shfl((int)bin, leader, 64);
    unsigned long long m = __ballot(pred && bin == lb);
    if (lane == leader) atomicAdd(&h[lb], (unsigned)__popcll(m));
    rem &= ~m;
  }
}

// 4 lanes per anchor; argmax on raw logits; one exact sigmoid per anchor;
// fused per-block LDS histogram of key[31:20] merged to ghist1 (nonzero bins only).
__launch_bounds__(1024)
__global__ void k_score(const float* __restrict__ cls, float* __restrict__ scores,
                        int* __restrict__ labels, unsigned* __restrict__ ghist1, int M) {
  __shared__ unsigned h1[4096];
  const int t = threadIdx.x;
  #pragma unroll
  for (int k = 0; k < 4; ++k) h1[t + 1024 * k] = 0u;
  __syncthreads();

  int gid = blockIdx.x * 1024 + t;
  int anchor = gid >> 2;
  int q = gid & 3;
  bool act = anchor < M;
  float lv[20];
  float best = -3.4e38f; int bc = 0;
  if (act) {
    const float4* row = reinterpret_cast<const float4*>(cls) + (size_t)anchor * (NCLS / 4);
    #pragma unroll
    for (int k = 0; k < 5; ++k) {
      float4 v = row[q + 4 * k];
      int cbase = (q + 4 * k) * 4;
      lv[4 * k + 0] = v.x; lv[4 * k + 1] = v.y; lv[4 * k + 2] = v.z; lv[4 * k + 3] = v.w;
      if (v.x > best) { best = v.x; bc = cbase + 0; }
      if (v.y > best) { best = v.y; bc = cbase + 1; }
      if (v.z > best) { best = v.z; bc = cbase + 2; }
      if (v.w > best) { best = v.w; bc = cbase + 3; }
    }
  } else {
    #pragma unroll
    for (int k = 0; k < 20; ++k) lv[k] = -3.4e38f;
  }
  #pragma unroll
  for (int d = 1; d < 4; d <<= 1) {
    float ob = __shfl_xor(best, d, 64);
    int oc = __shfl_xor(bc, d, 64);
    if (ob > best || (ob == best && oc < bc)) { best = ob; bc = oc; }
  }
  float s = sigmoid_np(best);
  // collision band: logit gap below this can round to the same float sigmoid
  float sp = s * (1.0f - s);
  float band = (s < 1.0f && sp > 0.0f) ? (4.8e-7f / sp) : 3.4e38f;  // 8 ulps margin
  float thresh = best - band;
  int cclose = 1 << 30;
  #pragma unroll
  for (int k = 0; k < 5; ++k) {
    #pragma unroll
    for (int j = 0; j < 4; ++j) {
      int c = (q + 4 * k) * 4 + j;
      if (lv[4 * k + j] >= thresh && c < cclose) cclose = c;
    }
  }
  #pragma unroll
  for (int d = 1; d < 4; d <<= 1) {
    int oc = __shfl_xor(cclose, d, 64);
    if (oc < cclose) cclose = oc;
  }
  int lab = bc;
  if (act && cclose < bc && q == 0) {  // rare: exact serial argmax over rounded sigmoids
    float bp = -1.0f; int bl = 0;
    for (int c = 0; c < NCLS; ++c) {
      float p = sigmoid_np(cls[(size_t)anchor * NCLS + c]);
      if (p > bp) { bp = p; bl = c; }
    }
    lab = bl;
  }
  if (act && q == 0) {
    scores[anchor] = s;
    labels[anchor] = lab;
  }
  agg_add(h1, fkey(s) >> 20, act && q == 0);
  __syncthreads();
  #pragma unroll
  for (int k = 0; k < 4; ++k) {
    unsigned c = h1[t + 1024 * k];
    if (c) atomicAdd(&ghist1[t + 1024 * k], c);
  }
}

// Each block recomputes B1 (coarse threshold bin) from ghist1, then histograms
// key bits [19:8] of elements in bin B1 into global ghist2. Block 0 stores meta.
__launch_bounds__(1024)
__global__ void k_hist2(const unsigned* __restrict__ ghist1, const float* __restrict__ scores,
                        unsigned* __restrict__ ghist2, unsigned* __restrict__ gmeta, int M) {
  __shared__ unsigned chunks[1024];
  __shared__ int sB1; __shared__ unsigned sAb;
  const int t = threadIdx.x;
  unsigned hb0 = ghist1[4 * t], hb1 = ghist1[4 * t + 1],
           hb2 = ghist1[4 * t + 2], hb3 = ghist1[4 * t + 3];
  chunks[t] = hb0 + hb1 + hb2 + hb3;
  __syncthreads();
  for (int d = 1; d < 1024; d <<= 1) {   // inclusive suffix sum
    unsigned v = chunks[t] + ((t + d < 1024) ? chunks[t + d] : 0u);
    __syncthreads();
    chunks[t] = v;
    __syncthreads();
  }
  {
    unsigned ssc = chunks[t];
    unsigned ssn = (t + 1 < 1024) ? chunks[t + 1] : 0u;
    if (ssc >= (unsigned)TOPK && ssn < (unsigned)TOPK) {
      unsigned hb[4] = {hb0, hb1, hb2, hb3};
      unsigned run = ssn;
      for (int b = 3; b >= 0; --b) {
        run += hb[b];
        if (run >= (unsigned)TOPK) { sB1 = 4 * t + b; sAb = run - hb[b]; break; }
      }
    }
  }
  __syncthreads();
  const unsigned B1 = (unsigned)sB1;
  if (blockIdx.x == 0 && t == 0) { gmeta[0] = B1; gmeta[1] = sAb; }

  int base = (blockIdx.x * 1024 + t) * 4;
  if (base + 3 < M) {
    float4 v = *reinterpret_cast<const float4*>(scores + base);
    unsigned k0 = fkey(v.x), k1 = fkey(v.y), k2 = fkey(v.z), k3 = fkey(v.w);
    if ((k0 >> 20) == B1) atomicAdd(&ghist2[(k0 >> 8) & 0xFFFu], 1u);
    if ((k1 >> 20) == B1) atomicAdd(&ghist2[(k1 >> 8) & 0xFFFu], 1u);
    if ((k2 >> 20) == B1) atomicAdd(&ghist2[(k2 >> 8) & 0xFFFu], 1u);
    if ((k3 >> 20) == B1) atomicAdd(&ghist2[(k3 >> 8) & 0xFFFu], 1u);
  } else {
    for (int j = base; j < M; ++j) {
      unsigned k0 = fkey(scores[j]);
      if ((k0 >> 20) == B1) atomicAdd(&ghist2[(k0 >> 8) & 0xFFFu], 1u);
    }
  }
}

// Each block recomputes the 24-bit threshold T from ghist2+meta, then compacts
// its slice of keys >= T into the global candidate buffer (1 atomic per block).
__launch_bounds__(1024)
__global__ void k_compact(const unsigned* __restrict__ ghist2, const unsigned* __restrict__ gmeta,
                          const float* __restrict__ scores,
                          unsigned long long* __restrict__ cand, unsigned* __restrict__ gcount,
                          int M) {
  __shared__ unsigned chunks[1024];
  __shared__ int sB2;
  __shared__ unsigned wcnt[16];
  __shared__ unsigned sbase;
  const int t = threadIdx.x;
  const unsigned B1 = gmeta[0], nAb = gmeta[1];
  unsigned hb0 = ghist2[4 * t], hb1 = ghist2[4 * t + 1],
           hb2 = ghist2[4 * t + 2], hb3 = ghist2[4 * t + 3];
  chunks[t] = hb0 + hb1 + hb2 + hb3;
  __syncthreads();
  for (int d = 1; d < 1024; d <<= 1) {
    unsigned v = chunks[t] + ((t + d < 1024) ? chunks[t + d] : 0u);
    __syncthreads();
    chunks[t] = v;
    __syncthreads();
  }
  {
    unsigned ssc = nAb + chunks[t];
    unsigned ssn = nAb + ((t + 1 < 1024) ? chunks[t + 1] : 0u);
    if (ssc >= (unsigned)TOPK && ssn < (unsigned)TOPK) {
      unsigned hb[4] = {hb0, hb1, hb2, hb3};
      unsigned run = ssn;
      for (int b = 3; b >= 0; --b) {
        run += hb[b];
        if (run >= (unsigned)TOPK) { sB2 = 4 * t + b; break; }
      }
    }
  }
  __syncthreads();
  const unsigned T = (B1 << 20) | ((unsigned)sB2 << 8);

  int base = (blockIdx.x * 1024 + t) * 4;
  unsigned keys[4]; int idxs[4]; int np = 0;
  #pragma unroll
  for (int j = 0; j < 4; ++j) {
    int i = base + j;
    if (i < M) {
      unsigned key = fkey(scores[i]);
      if (key >= T) { keys[np] = key; idxs[np] = i; ++np; }
    }
  }
  // wave inclusive scan of np
  const int lane = t & 63, wid = t >> 6;
  int sc = np;
  #pragma unroll
  for (int d = 1; d < 64; d <<= 1) {
    int o = __shfl_up(sc, d, 64);
    if (lane >= d) sc += o;
  }
  if (lane == 63) wcnt[wid] = (unsigned)sc;
  __syncthreads();
  if (t == 0) {
    unsigned acc = 0;
    for (int w = 0; w < 16; ++w) { unsigned v = wcnt[w]; wcnt[w] = acc; acc += v; }
    sbase = acc ? atomicAdd(gcount, acc) : 0u;
  }
  __syncthreads();
  unsigned pos = sbase + wcnt[wid] + (unsigned)(sc - np);
  for (int j = 0; j < np; ++j) {
    if (pos < (unsigned)CAND_CAP)
      cand[pos] = ((unsigned long long)keys[j] << 32) | (unsigned)(~(unsigned)idxs[j]);
    ++pos;
  }
}

// Exact rank (N^2 over <=CAND_CAP distinct keys) + decode, one block.
__launch_bounds__(1024)
__global__ void k_rank(const unsigned long long* __restrict__ cand, const unsigned* __restrict__ gcount,
                       const int* __restrict__ labels, const float* __restrict__ reg,
                       const float* __restrict__ asz, const int* __restrict__ pW, int A,
                       float* __restrict__ sel_score, int* __restrict__ sel_label,
                       float* __restrict__ boxes, float* __restrict__ areas,
                       float* __restrict__ obox) {
  __shared__ unsigned long long ck[CAND_CAP];  // 32KB
  const int t = threadIdx.x;
  unsigned n = *gcount; if (n > (unsigned)CAND_CAP) n = (unsigned)CAND_CAP;
  for (int i = t; i < CAND_CAP; i += 1024) ck[i] = (i < (int)n) ? cand[i] : 0ull;
  __syncthreads();
  for (int c = t; c < (int)n; c += 1024) {
    unsigned long long my = ck[c];
    int r = 0;
    for (int j = 0; j < (int)n; ++j) r += (ck[j] > my);   // uniform j: LDS broadcast
    if (r < TOPK) {
      unsigned key = (unsigned)(my >> 32);
      unsigned u = (key & 0x80000000u) ? (key ^ 0x80000000u) : ~key;
      float scv = __uint_as_float(u);
      int idx = (int)(~(unsigned)my);
      int lab = labels[idx];
      int W = *pW;
      int a = idx % A;
      int cell = idx / A;
      int x = cell % W;
      int y = cell / W;
      float aw = asz[a * 2 + 0], ah = asz[a * 2 + 1];
      float ax = ((float)x + 0.5f) * 32.0f;
      float ay = ((float)y + 0.5f) * 32.0f;
      float4 rg = *reinterpret_cast<const float4*>(reg + (size_t)idx * 4);
      float offx = fminf(fmaxf(rg.x * aw, -32.0f), 32.0f);
      float offy = fminf(fmaxf(rg.y * ah, -32.0f), 32.0f);
      float cx = ax + offx, cy = ay + offy;
      const float SC = 4.135166556742356f;  // log(1000/16)
      float bw = aw * exp_np(fminf(rg.z, SC));
      float bh = ah * exp_np(fminf(rg.w, SC));
      float x1 = cx - 0.5f * bw, y1 = cy - 0.5f * bh;
      float x2 = cx + 0.5f * bw, y2 = cy + 0.5f * bh;
      float off = (float)lab * 100000.0f;
      float ox1 = x1 + off, oy1 = y1 + off, ox2 = x2 + off, oy2 = y2 + off;
      sel_score[r] = scv; sel_label[r] = lab;
      boxes[r * 4 + 0] = x1; boxes[r * 4 + 1] = y1;
      boxes[r * 4 + 2] = x2; boxes[r * 4 + 3] = y2;
      obox[0 * 1024 + r] = ox1; obox[1 * 1024 + r] = oy1;
      obox[2 * 1024 + r] = ox2; obox[3 * 1024 + r] = oy2;
      areas[r] = (ox2 - ox1) * (oy2 - oy1);  // areas on offset boxes, like the reference
    }
  }
}

// COLUMN-form mask: maskC[c*1024 + j] = u64 whose bit i says
// "box c*64+i suppresses box j" (IoU > thr, c*64+i < j). IoU is symmetric,
// so this is the old row-mask computation with i/j roles swapped.
// c is block-uniform (256 | 1024); inner i loop is block-uniform -> LDS broadcast.
__launch_bounds__(256)
__global__ void k_mask(const float* __restrict__ obox, const float* __restrict__ areas,
                       unsigned long long* __restrict__ maskC) {
  __shared__ float so0[1024], so1[1024], so2[1024], so3[1024], sa[1024];
  const int t = threadIdx.x;
  int g = blockIdx.x * 256 + t;
  int c = g >> 10, j = g & 1023;
  for (int idx = t; idx < 1024; idx += 256) {
    so0[idx] = obox[idx];        so1[idx] = obox[1024 + idx];
    so2[idx] = obox[2048 + idx]; so3[idx] = obox[3072 + idx];
    sa[idx] = areas[idx];
  }
  __syncthreads();
  if (j >= TOPK) { maskC[c * 1024 + j] = 0ull; return; }
  float x1j = so0[j], y1j = so1[j], x2j = so2[j], y2j = so3[j];
  float aj = sa[j];
  unsigned long long bits = 0ull;
  int i0 = c * 64;
  for (int ii = 0; ii < 64; ++ii) {
    int i = i0 + ii;                       // block-uniform: LDS broadcast
    if (i < TOPK && i < j) {
      float xx1 = fmaxf(so0[i], x1j);
      float yy1 = fmaxf(so1[i], y1j);
      float xx2 = fminf(so2[i], x2j);
      float yy2 = fminf(so3[i], y2j);
      float inter = fmaxf(1e-28f, xx2 - xx1) * fmaxf(1e-28f, yy2 - yy1);
      float uni = sa[i] + aj - inter + 1e-14f;
      float iou = inter / uni;             // IEEE division: bit-matches reference
      if (iou > 0.6f) bits |= (1ull << ii);
    }
  }
  maskC[c * 1024 + j] = bits;
}

// SINGLE-WAVE greedy NMS, serial only in KEPT boxes.
// Per 64-box block: `avail` is wave-uniform; each kept box costs
// ffs + one ballot (clears all its victims at once). Skipped boxes are free.
// Cross-block suppression: 15 ballots per block, batched after keeps final.
__launch_bounds__(64, 1)
__global__ void k_nms(const unsigned long long* __restrict__ maskC,
                      const float* __restrict__ sel_score, const int* __restrict__ sel_label,
                      const float* __restrict__ boxes,
                      const int* __restrict__ pW, const int* __restrict__ pH,
                      float* __restrict__ out) {
  const int lane = threadIdx.x;

  unsigned long long selfc[16];            // my column vs own block (static idx)
  #pragma unroll
  for (int f = 0; f < 16; ++f)
    selfc[f] = maskC[f * 1024 + f * 64 + lane];

  unsigned long long valid[16];            // wave-uniform ballots
  #pragma unroll
  for (int f = 0; f < 16; ++f) {
    int r = f * 64 + lane;
    bool ok = (r < TOPK) && (sel_score[r] >= 0.05f);
    valid[f] = __ballot(ok);
  }

  unsigned long long supp[16];
  #pragma unroll
  for (int f = 0; f < 16; ++f) supp[f] = 0ull;
  unsigned long long kw[16];

  #pragma unroll
  for (int f = 0; f < 16; ++f) {
    unsigned long long w[16];              // cross words, static idx under unroll
    #pragma unroll
    for (int g = f + 1; g < 16; ++g)
      w[g] = maskC[f * 1024 + g * 64 + lane];   // issued before the while loop

    unsigned long long ct = selfc[f];
    unsigned long long avail = valid[f] & ~supp[f];
    unsigned long long kwf = 0ull;
    while (avail) {
      int i = __ffsll((long long)avail) - 1;    // highest-score available box
      kwf |= (1ull << i);
      unsigned long long vict = __ballot(((ct >> i) & 1ull) != 0ull);
      avail &= ~vict;
      avail &= ~(1ull << i);
    }
    kw[f] = kwf;
    #pragma unroll
    for (int g = f + 1; g < 16; ++g) {
      bool hit = (w[g] & kwf) != 0ull;
      supp[g] |= __ballot(hit);
    }
  }

  // Fused output epilogue: kw[f] are wave-uniform scalars, static indexing.
  float sw = (float)(*pW * 32);
  float sh = (float)(*pH * 32);
  const float4* b4 = reinterpret_cast<const float4*>(boxes);
  #pragma unroll
  for (int f = 0; f < 16; ++f) {
    int r = f * 64 + lane;
    if (r < TOPK) {
      bool kp = (kw[f] >> lane) & 1ull;
      float m = kp ? 1.0f : 0.0f;
      float4 b = b4[r];
      float b0 = fminf(fmaxf(b.x / sw, 0.0f), 1.0f) * m;
      float b1 = fminf(fmaxf(b.y / sh, 0.0f), 1.0f) * m;
      float b2 = fminf(fmaxf(b.z / sw, 0.0f), 1.0f) * m;
      float b3 = fminf(fmaxf(b.w / sh, 0.0f), 1.0f) * m;
      out[r * 4 + 0] = b0; out[r * 4 + 1] = b1;
      out[r * 4 + 2] = b2; out[r * 4 + 3] = b3;
      out[TOPK * 4 + r] = sel_score[r] * m;
      out[TOPK * 5 + r] = kp ? (float)sel_label[r] : -1.0f;
      out[TOPK * 6 + r] = m;
    }
  }
}

extern "C" void kernel_launch(void* const* d_in, const int* in_sizes, int n_in,
                              void* d_out, int out_size, void* d_ws, size_t ws_size,
                              hipStream_t stream) {
  const float* cls = (const float*)d_in[0];
  const float* reg = (const float*)d_in[1];
  const float* asz = (const float*)d_in[2];
  const int* pH = (const int*)d_in[3];
  const int* pW = (const int*)d_in[4];
  int M = in_sizes[0] / NCLS;
  int A = in_sizes[2] / 2;

  char* ws = (char*)d_ws;
  size_t off = 0;
  auto alloc = [&](size_t bytes) { size_t o = off; off = (off + bytes + 255) & ~(size_t)255; return o; };
  size_t o_h1    = alloc(4096 * sizeof(unsigned));
  size_t o_h2    = alloc(4096 * sizeof(unsigned));
  size_t o_misc  = alloc(256);                       // gcount @ +0, gmeta @ +8
  size_t zero_end = off;
  size_t o_cand  = alloc((size_t)CAND_CAP * sizeof(unsigned long long));
  size_t o_sc    = alloc((size_t)M * sizeof(float));
  size_t o_lb    = alloc((size_t)M * sizeof(int));
  size_t o_ssc   = alloc(1024 * sizeof(float));
  size_t o_slb   = alloc(1024 * sizeof(int));
  size_t o_box   = alloc((size_t)TOPK * 4 * sizeof(float));
  size_t o_area  = alloc(1024 * sizeof(float));
  size_t o_obox  = alloc(4 * 1024 * sizeof(float));
  size_t o_mask  = alloc((size_t)NWORDS * 1024 * sizeof(unsigned long long));
  (void)ws_size; (void)out_size; (void)n_in;

  hipMemsetAsync(ws, 0, zero_end, stream);   // ghist1 + ghist2 + gcount/gmeta

  int nblk_score = (M * 4 + 1023) / 1024;
  k_score<<<nblk_score, 1024, 0, stream>>>(
      cls, (float*)(ws + o_sc), (int*)(ws + o_lb), (unsigned*)(ws + o_h1), M);

  int nblk_scan = ((M + 3) / 4 + 1023) / 1024;
  k_hist2<<<nblk_scan, 1024, 0, stream>>>(
      (const unsigned*)(ws + o_h1), (const float*)(ws + o_sc),
      (unsigned*)(ws + o_h2), (unsigned*)(ws + o_misc + 8), M);
  k_compact<<<nblk_scan, 1024, 0, stream>>>(
      (const unsigned*)(ws + o_h2), (const unsigned*)(ws + o_misc + 8),
      (const float*)(ws + o_sc),
      (unsigned long long*)(ws + o_cand), (unsigned*)(ws + o_misc), M);
  k_rank<<<1, 1024, 0, stream>>>(
      (const unsigned long long*)(ws + o_cand), (const unsigned*)(ws + o_misc),
      (const int*)(ws + o_lb), reg, asz, pW, A,
      (float*)(ws + o_ssc), (int*)(ws + o_slb),
      (float*)(ws + o_box), (float*)(ws + o_area), (float*)(ws + o_obox));
  k_mask<<<(NWORDS * 1024) / 256, 256, 0, stream>>>(
      (const float*)(ws + o_obox), (const float*)(ws + o_area),
      (unsigned long long*)(ws + o_mask));
  k_nms<<<1, 64, 0, stream>>>(
      (const unsigned long long*)(ws + o_mask),
      (const float*)(ws + o_ssc), (const int*)(ws + o_slb),
      (const float*)(ws + o_box), pW, pH, (float*)d_out);
}

// Round 8
// 110.574 us; speedup vs baseline: 1.5162x; 1.0148x over previous
//
#include <hip/hip_runtime.h>
#include <math.h>

#define NCLS 80
#define TOPK 1000
#define NWORDS 16          // ceil(1000/64)
#define CAND_CAP 4096

// Correctly-rounded float sigmoid: matches numpy's 1/(1+np.exp(-x)) bit-for-bit.
__device__ __forceinline__ float sigmoid_np(float x) {
  float e = (float)exp(-(double)x);
  return 1.0f / (1.0f + e);
}
__device__ __forceinline__ float exp_np(float x) { return (float)exp((double)x); }

// monotonic float->uint key
__device__ __forceinline__ unsigned fkey(float s) {
  unsigned u = __float_as_uint(s);
  return ((int)u < 0) ? ~u : (u | 0x80000000u);
}

// Wave-aggregated LDS histogram add: one atomic per distinct bin per wave.
__device__ __forceinline__ void agg_add(unsigned* h, unsigned bin, bool pred) {
  unsigned long long rem = __ballot(pred);
  const int lane = threadIdx.x & 63;
  while (rem) {
    int leader = __ffsll(rem) - 1;
    unsigned lb = (unsigned)__shfl((int)bin, leader, 64);
    unsigned long long m = __ballot(pred && bin == lb);
    if (lane == leader) atomicAdd(&h[lb], (unsigned)__popcll(m));
    rem &= ~m;
  }
}

// 4 lanes per anchor; argmax on raw logits; one exact sigmoid per anchor;
// fused per-block LDS histogram of key[31:20] merged to ghist1 (nonzero bins only).
__launch_bounds__(1024)
__global__ void k_score(const float* __restrict__ cls, float* __restrict__ scores,
                        int* __restrict__ labels, unsigned* __restrict__ ghist1, int M) {
  __shared__ unsigned h1[4096];
  const int t = threadIdx.x;
  #pragma unroll
  for (int k = 0; k < 4; ++k) h1[t + 1024 * k] = 0u;
  __syncthreads();

  int gid = blockIdx.x * 1024 + t;
  int anchor = gid >> 2;
  int q = gid & 3;
  bool act = anchor < M;
  float lv[20];
  float best = -3.4e38f; int bc = 0;
  if (act) {
    const float4* row = reinterpret_cast<const float4*>(cls) + (size_t)anchor * (NCLS / 4);
    #pragma unroll
    for (int k = 0; k < 5; ++k) {
      float4 v = row[q + 4 * k];
      int cbase = (q + 4 * k) * 4;
      lv[4 * k + 0] = v.x; lv[4 * k + 1] = v.y; lv[4 * k + 2] = v.z; lv[4 * k + 3] = v.w;
      if (v.x > best) { best = v.x; bc = cbase + 0; }
      if (v.y > best) { best = v.y; bc = cbase + 1; }
      if (v.z > best) { best = v.z; bc = cbase + 2; }
      if (v.w > best) { best = v.w; bc = cbase + 3; }
    }
  } else {
    #pragma unroll
    for (int k = 0; k < 20; ++k) lv[k] = -3.4e38f;
  }
  #pragma unroll
  for (int d = 1; d < 4; d <<= 1) {
    float ob = __shfl_xor(best, d, 64);
    int oc = __shfl_xor(bc, d, 64);
    if (ob > best || (ob == best && oc < bc)) { best = ob; bc = oc; }
  }
  float s = sigmoid_np(best);
  // collision band: logit gap below this can round to the same float sigmoid
  float sp = s * (1.0f - s);
  float band = (s < 1.0f && sp > 0.0f) ? (4.8e-7f / sp) : 3.4e38f;  // 8 ulps margin
  float thresh = best - band;
  int cclose = 1 << 30;
  #pragma unroll
  for (int k = 0; k < 5; ++k) {
    #pragma unroll
    for (int j = 0; j < 4; ++j) {
      int c = (q + 4 * k) * 4 + j;
      if (lv[4 * k + j] >= thresh && c < cclose) cclose = c;
    }
  }
  #pragma unroll
  for (int d = 1; d < 4; d <<= 1) {
    int oc = __shfl_xor(cclose, d, 64);
    if (oc < cclose) cclose = oc;
  }
  int lab = bc;
  if (act && cclose < bc && q == 0) {  // rare: exact serial argmax over rounded sigmoids
    float bp = -1.0f; int bl = 0;
    for (int c = 0; c < NCLS; ++c) {
      float p = sigmoid_np(cls[(size_t)anchor * NCLS + c]);
      if (p > bp) { bp = p; bl = c; }
    }
    lab = bl;
  }
  if (act && q == 0) {
    scores[anchor] = s;
    labels[anchor] = lab;
  }
  agg_add(h1, fkey(s) >> 20, act && q == 0);
  __syncthreads();
  #pragma unroll
  for (int k = 0; k < 4; ++k) {
    unsigned c = h1[t + 1024 * k];
    if (c) atomicAdd(&ghist1[t + 1024 * k], c);
  }
}

// Each block recomputes B1 (coarse threshold bin) from ghist1, then histograms
// key bits [19:8] of elements in bin B1 into global ghist2. Block 0 stores meta.
__launch_bounds__(1024)
__global__ void k_hist2(const unsigned* __restrict__ ghist1, const float* __restrict__ scores,
                        unsigned* __restrict__ ghist2, unsigned* __restrict__ gmeta, int M) {
  __shared__ unsigned chunks[1024];
  __shared__ int sB1; __shared__ unsigned sAb;
  const int t = threadIdx.x;
  unsigned hb0 = ghist1[4 * t], hb1 = ghist1[4 * t + 1],
           hb2 = ghist1[4 * t + 2], hb3 = ghist1[4 * t + 3];
  chunks[t] = hb0 + hb1 + hb2 + hb3;
  __syncthreads();
  for (int d = 1; d < 1024; d <<= 1) {   // inclusive suffix sum
    unsigned v = chunks[t] + ((t + d < 1024) ? chunks[t + d] : 0u);
    __syncthreads();
    chunks[t] = v;
    __syncthreads();
  }
  {
    unsigned ssc = chunks[t];
    unsigned ssn = (t + 1 < 1024) ? chunks[t + 1] : 0u;
    if (ssc >= (unsigned)TOPK && ssn < (unsigned)TOPK) {
      unsigned hb[4] = {hb0, hb1, hb2, hb3};
      unsigned run = ssn;
      for (int b = 3; b >= 0; --b) {
        run += hb[b];
        if (run >= (unsigned)TOPK) { sB1 = 4 * t + b; sAb = run - hb[b]; break; }
      }
    }
  }
  __syncthreads();
  const unsigned B1 = (unsigned)sB1;
  if (blockIdx.x == 0 && t == 0) { gmeta[0] = B1; gmeta[1] = sAb; }

  int base = (blockIdx.x * 1024 + t) * 4;
  if (base + 3 < M) {
    float4 v = *reinterpret_cast<const float4*>(scores + base);
    unsigned k0 = fkey(v.x), k1 = fkey(v.y), k2 = fkey(v.z), k3 = fkey(v.w);
    if ((k0 >> 20) == B1) atomicAdd(&ghist2[(k0 >> 8) & 0xFFFu], 1u);
    if ((k1 >> 20) == B1) atomicAdd(&ghist2[(k1 >> 8) & 0xFFFu], 1u);
    if ((k2 >> 20) == B1) atomicAdd(&ghist2[(k2 >> 8) & 0xFFFu], 1u);
    if ((k3 >> 20) == B1) atomicAdd(&ghist2[(k3 >> 8) & 0xFFFu], 1u);
  } else {
    for (int j = base; j < M; ++j) {
      unsigned k0 = fkey(scores[j]);
      if ((k0 >> 20) == B1) atomicAdd(&ghist2[(k0 >> 8) & 0xFFFu], 1u);
    }
  }
}

// Each block recomputes the 24-bit threshold T from ghist2+meta, then compacts
// its slice of keys >= T into the global candidate buffer (1 atomic per block).
__launch_bounds__(1024)
__global__ void k_compact(const unsigned* __restrict__ ghist2, const unsigned* __restrict__ gmeta,
                          const float* __restrict__ scores,
                          unsigned long long* __restrict__ cand, unsigned* __restrict__ gcount,
                          int M) {
  __shared__ unsigned chunks[1024];
  __shared__ int sB2;
  __shared__ unsigned wcnt[16];
  __shared__ unsigned sbase;
  const int t = threadIdx.x;
  const unsigned B1 = gmeta[0], nAb = gmeta[1];
  unsigned hb0 = ghist2[4 * t], hb1 = ghist2[4 * t + 1],
           hb2 = ghist2[4 * t + 2], hb3 = ghist2[4 * t + 3];
  chunks[t] = hb0 + hb1 + hb2 + hb3;
  __syncthreads();
  for (int d = 1; d < 1024; d <<= 1) {
    unsigned v = chunks[t] + ((t + d < 1024) ? chunks[t + d] : 0u);
    __syncthreads();
    chunks[t] = v;
    __syncthreads();
  }
  {
    unsigned ssc = nAb + chunks[t];
    unsigned ssn = nAb + ((t + 1 < 1024) ? chunks[t + 1] : 0u);
    if (ssc >= (unsigned)TOPK && ssn < (unsigned)TOPK) {
      unsigned hb[4] = {hb0, hb1, hb2, hb3};
      unsigned run = ssn;
      for (int b = 3; b >= 0; --b) {
        run += hb[b];
        if (run >= (unsigned)TOPK) { sB2 = 4 * t + b; break; }
      }
    }
  }
  __syncthreads();
  const unsigned T = (B1 << 20) | ((unsigned)sB2 << 8);

  int base = (blockIdx.x * 1024 + t) * 4;
  unsigned keys[4]; int idxs[4]; int np = 0;
  #pragma unroll
  for (int j = 0; j < 4; ++j) {
    int i = base + j;
    if (i < M) {
      unsigned key = fkey(scores[i]);
      if (key >= T) { keys[np] = key; idxs[np] = i; ++np; }
    }
  }
  // wave inclusive scan of np
  const int lane = t & 63, wid = t >> 6;
  int sc = np;
  #pragma unroll
  for (int d = 1; d < 64; d <<= 1) {
    int o = __shfl_up(sc, d, 64);
    if (lane >= d) sc += o;
  }
  if (lane == 63) wcnt[wid] = (unsigned)sc;
  __syncthreads();
  if (t == 0) {
    unsigned acc = 0;
    for (int w = 0; w < 16; ++w) { unsigned v = wcnt[w]; wcnt[w] = acc; acc += v; }
    sbase = acc ? atomicAdd(gcount, acc) : 0u;
  }
  __syncthreads();
  unsigned pos = sbase + wcnt[wid] + (unsigned)(sc - np);
  for (int j = 0; j < np; ++j) {
    if (pos < (unsigned)CAND_CAP)
      cand[pos] = ((unsigned long long)keys[j] << 32) | (unsigned)(~(unsigned)idxs[j]);
    ++pos;
  }
}

// Exact rank (N^2 over <=CAND_CAP distinct keys) + decode, one block.
__launch_bounds__(1024)
__global__ void k_rank(const unsigned long long* __restrict__ cand, const unsigned* __restrict__ gcount,
                       const int* __restrict__ labels, const float* __restrict__ reg,
                       const float* __restrict__ asz, const int* __restrict__ pW, int A,
                       float* __restrict__ sel_score, int* __restrict__ sel_label,
                       float* __restrict__ boxes, float* __restrict__ areas,
                       float* __restrict__ obox) {
  __shared__ unsigned long long ck[CAND_CAP];  // 32KB
  const int t = threadIdx.x;
  unsigned n = *gcount; if (n > (unsigned)CAND_CAP) n = (unsigned)CAND_CAP;
  for (int i = t; i < CAND_CAP; i += 1024) ck[i] = (i < (int)n) ? cand[i] : 0ull;
  __syncthreads();
  for (int c = t; c < (int)n; c += 1024) {
    unsigned long long my = ck[c];
    int r = 0;
    for (int j = 0; j < (int)n; ++j) r += (ck[j] > my);   // uniform j: LDS broadcast
    if (r < TOPK) {
      unsigned key = (unsigned)(my >> 32);
      unsigned u = (key & 0x80000000u) ? (key ^ 0x80000000u) : ~key;
      float scv = __uint_as_float(u);
      int idx = (int)(~(unsigned)my);
      int lab = labels[idx];
      int W = *pW;
      int a = idx % A;
      int cell = idx / A;
      int x = cell % W;
      int y = cell / W;
      float aw = asz[a * 2 + 0], ah = asz[a * 2 + 1];
      float ax = ((float)x + 0.5f) * 32.0f;
      float ay = ((float)y + 0.5f) * 32.0f;
      float4 rg = *reinterpret_cast<const float4*>(reg + (size_t)idx * 4);
      float offx = fminf(fmaxf(rg.x * aw, -32.0f), 32.0f);
      float offy = fminf(fmaxf(rg.y * ah, -32.0f), 32.0f);
      float cx = ax + offx, cy = ay + offy;
      const float SC = 4.135166556742356f;  // log(1000/16)
      float bw = aw * exp_np(fminf(rg.z, SC));
      float bh = ah * exp_np(fminf(rg.w, SC));
      float x1 = cx - 0.5f * bw, y1 = cy - 0.5f * bh;
      float x2 = cx + 0.5f * bw, y2 = cy + 0.5f * bh;
      float off = (float)lab * 100000.0f;
      float ox1 = x1 + off, oy1 = y1 + off, ox2 = x2 + off, oy2 = y2 + off;
      sel_score[r] = scv; sel_label[r] = lab;
      boxes[r * 4 + 0] = x1; boxes[r * 4 + 1] = y1;
      boxes[r * 4 + 2] = x2; boxes[r * 4 + 3] = y2;
      obox[0 * 1024 + r] = ox1; obox[1 * 1024 + r] = oy1;
      obox[2 * 1024 + r] = ox2; obox[3 * 1024 + r] = oy2;
      areas[r] = (ox2 - ox1) * (oy2 - oy1);  // areas on offset boxes, like the reference
    }
  }
}

// COLUMN-form mask: maskC[c*1024 + j] = u64 whose bit i says
// "box c*64+i suppresses box j" (IoU > thr, c*64+i < j). IoU is symmetric,
// so this is the old row-mask computation with i/j roles swapped.
// c is block-uniform (256 | 1024); inner i loop is block-uniform -> LDS broadcast.
__launch_bounds__(256)
__global__ void k_mask(const float* __restrict__ obox, const float* __restrict__ areas,
                       unsigned long long* __restrict__ maskC) {
  __shared__ float so0[1024], so1[1024], so2[1024], so3[1024], sa[1024];
  const int t = threadIdx.x;
  int g = blockIdx.x * 256 + t;
  int c = g >> 10, j = g & 1023;
  for (int idx = t; idx < 1024; idx += 256) {
    so0[idx] = obox[idx];        so1[idx] = obox[1024 + idx];
    so2[idx] = obox[2048 + idx]; so3[idx] = obox[3072 + idx];
    sa[idx] = areas[idx];
  }
  __syncthreads();
  if (j >= TOPK) { maskC[c * 1024 + j] = 0ull; return; }
  float x1j = so0[j], y1j = so1[j], x2j = so2[j], y2j = so3[j];
  float aj = sa[j];
  unsigned long long bits = 0ull;
  int i0 = c * 64;
  for (int ii = 0; ii < 64; ++ii) {
    int i = i0 + ii;                       // block-uniform: LDS broadcast
    if (i < TOPK && i < j) {
      float xx1 = fmaxf(so0[i], x1j);
      float yy1 = fmaxf(so1[i], y1j);
      float xx2 = fminf(so2[i], x2j);
      float yy2 = fminf(so3[i], y2j);
      float inter = fmaxf(1e-28f, xx2 - xx1) * fmaxf(1e-28f, yy2 - yy1);
      float uni = sa[i] + aj - inter + 1e-14f;
      float iou = inter / uni;             // IEEE division: bit-matches reference
      if (iou > 0.6f) bits |= (1ull << ii);
    }
  }
  maskC[c * 1024 + j] = bits;
}

// SINGLE-WAVE greedy NMS, serial only in KEPT boxes; all mask words staged
// to LDS in one pipelined burst (R7: 136 serialized global loads at 48 VGPR
// were ~50us of pure latency). tri(f,g) packs the upper triangle: row index
// = 16f - f(f-1)/2 + (g-f), all static under full unroll.
#define TRI_IDX(f, g) ((f) * 16 - ((f) * ((f) - 1)) / 2 + ((g) - (f)))

__launch_bounds__(64, 1)
__global__ void k_nms(const unsigned long long* __restrict__ maskC,
                      const float* __restrict__ sel_score, const int* __restrict__ sel_label,
                      const float* __restrict__ boxes,
                      const int* __restrict__ pW, const int* __restrict__ pH,
                      float* __restrict__ out) {
  __shared__ unsigned long long sm[136 * 64];   // 68 KB: upper-tri mask words
  const int lane = threadIdx.x;

  // ---- burst stage: 136 coalesced loads, no inter-load dependencies ----
  #pragma unroll
  for (int f = 0; f < 16; ++f)
    #pragma unroll
    for (int g = f; g < 16; ++g)
      sm[TRI_IDX(f, g) * 64 + lane] = maskC[f * 1024 + g * 64 + lane];

  // epilogue operands prefetched in the same burst (registers, static idx)
  float sscore[16]; int slab[16]; float4 sbox[16];
  const float4* b4 = reinterpret_cast<const float4*>(boxes);
  #pragma unroll
  for (int f = 0; f < 16; ++f) {
    int r = f * 64 + lane;
    bool in = r < TOPK;
    sscore[f] = in ? sel_score[r] : 0.0f;
    slab[f] = in ? sel_label[r] : 0;
    sbox[f] = in ? b4[r] : make_float4(0.f, 0.f, 0.f, 0.f);
  }
  float sw = (float)(*pW * 32);
  float sh = (float)(*pH * 32);

  unsigned long long valid[16];            // wave-uniform ballots
  #pragma unroll
  for (int f = 0; f < 16; ++f) {
    int r = f * 64 + lane;
    valid[f] = __ballot((r < TOPK) && (sscore[f] >= 0.05f));
  }
  __syncthreads();

  unsigned long long supp[16];
  #pragma unroll
  for (int f = 0; f < 16; ++f) supp[f] = 0ull;
  unsigned long long kw[16];

  #pragma unroll
  for (int f = 0; f < 16; ++f) {
    unsigned long long ct = sm[TRI_IDX(f, f) * 64 + lane];
    unsigned long long avail = valid[f] & ~supp[f];
    unsigned long long kwf = 0ull;
    while (avail) {
      int i = __ffsll((long long)avail) - 1;    // highest-score available box
      kwf |= (1ull << i);
      unsigned long long vict = __ballot(((ct >> i) & 1ull) != 0ull);
      avail &= ~vict;
      avail &= ~(1ull << i);
    }
    kw[f] = kwf;
    #pragma unroll
    for (int g = f + 1; g < 16; ++g) {
      bool hit = (sm[TRI_IDX(f, g) * 64 + lane] & kwf) != 0ull;
      supp[g] |= __ballot(hit);
    }
  }

  // Fused output epilogue: kw[f] wave-uniform, operands already in registers.
  #pragma unroll
  for (int f = 0; f < 16; ++f) {
    int r = f * 64 + lane;
    if (r < TOPK) {
      bool kp = (kw[f] >> lane) & 1ull;
      float m = kp ? 1.0f : 0.0f;
      float4 b = sbox[f];
      float b0 = fminf(fmaxf(b.x / sw, 0.0f), 1.0f) * m;
      float b1 = fminf(fmaxf(b.y / sh, 0.0f), 1.0f) * m;
      float b2 = fminf(fmaxf(b.z / sw, 0.0f), 1.0f) * m;
      float b3 = fminf(fmaxf(b.w / sh, 0.0f), 1.0f) * m;
      out[r * 4 + 0] = b0; out[r * 4 + 1] = b1;
      out[r * 4 + 2] = b2; out[r * 4 + 3] = b3;
      out[TOPK * 4 + r] = sscore[f] * m;
      out[TOPK * 5 + r] = kp ? (float)slab[f] : -1.0f;
      out[TOPK * 6 + r] = m;
    }
  }
}

extern "C" void kernel_launch(void* const* d_in, const int* in_sizes, int n_in,
                              void* d_out, int out_size, void* d_ws, size_t ws_size,
                              hipStream_t stream) {
  const float* cls = (const float*)d_in[0];
  const float* reg = (const float*)d_in[1];
  const float* asz = (const float*)d_in[2];
  const int* pH = (const int*)d_in[3];
  const int* pW = (const int*)d_in[4];
  int M = in_sizes[0] / NCLS;
  int A = in_sizes[2] / 2;

  char* ws = (char*)d_ws;
  size_t off = 0;
  auto alloc = [&](size_t bytes) { size_t o = off; off = (off + bytes + 255) & ~(size_t)255; return o; };
  size_t o_h1    = alloc(4096 * sizeof(unsigned));
  size_t o_h2    = alloc(4096 * sizeof(unsigned));
  size_t o_misc  = alloc(256);                       // gcount @ +0, gmeta @ +8
  size_t zero_end = off;
  size_t o_cand  = alloc((size_t)CAND_CAP * sizeof(unsigned long long));
  size_t o_sc    = alloc((size_t)M * sizeof(float));
  size_t o_lb    = alloc((size_t)M * sizeof(int));
  size_t o_ssc   = alloc(1024 * sizeof(float));
  size_t o_slb   = alloc(1024 * sizeof(int));
  size_t o_box   = alloc((size_t)TOPK * 4 * sizeof(float));
  size_t o_area  = alloc(1024 * sizeof(float));
  size_t o_obox  = alloc(4 * 1024 * sizeof(float));
  size_t o_mask  = alloc((size_t)NWORDS * 1024 * sizeof(unsigned long long));
  (void)ws_size; (void)out_size; (void)n_in;

  hipMemsetAsync(ws, 0, zero_end, stream);   // ghist1 + ghist2 + gcount/gmeta

  int nblk_score = (M * 4 + 1023) / 1024;
  k_score<<<nblk_score, 1024, 0, stream>>>(
      cls, (float*)(ws + o_sc), (int*)(ws + o_lb), (unsigned*)(ws + o_h1), M);

  int nblk_scan = ((M + 3) / 4 + 1023) / 1024;
  k_hist2<<<nblk_scan, 1024, 0, stream>>>(
      (const unsigned*)(ws + o_h1), (const float*)(ws + o_sc),
      (unsigned*)(ws + o_h2), (unsigned*)(ws + o_misc + 8), M);
  k_compact<<<nblk_scan, 1024, 0, stream>>>(
      (const unsigned*)(ws + o_h2), (const unsigned*)(ws + o_misc + 8),
      (const float*)(ws + o_sc),
      (unsigned long long*)(ws + o_cand), (unsigned*)(ws + o_misc), M);
  k_rank<<<1, 1024, 0, stream>>>(
      (const unsigned long long*)(ws + o_cand), (const unsigned*)(ws + o_misc),
      (const int*)(ws + o_lb), reg, asz, pW, A,
      (float*)(ws + o_ssc), (int*)(ws + o_slb),
      (float*)(ws + o_box), (float*)(ws + o_area), (float*)(ws + o_obox));
  k_mask<<<(NWORDS * 1024) / 256, 256, 0, stream>>>(
      (const float*)(ws + o_obox), (const float*)(ws + o_area),
      (unsigned long long*)(ws + o_mask));
  k_nms<<<1, 64, 0, stream>>>(
      (const unsigned long long*)(ws + o_mask),
      (const float*)(ws + o_ssc), (const int*)(ws + o_slb),
      (const float*)(ws + o_box), pW, pH, (float*)d_out);
}

// Round 9
// 76.773 us; speedup vs baseline: 2.1838x; 1.4403x over previous
//
#include <hip/hip_runtime.h>
#include <math.h>

#define NCLS 80
#define TOPK 1000
#define NWORDS 16          // ceil(1000/64)
#define CAND_CAP 4096

// Correctly-rounded float sigmoid: matches numpy's 1/(1+np.exp(-x)) bit-for-bit.
__device__ __forceinline__ float sigmoid_np(float x) {
  float e = (float)exp(-(double)x);
  return 1.0f / (1.0f + e);
}
__device__ __forceinline__ float exp_np(float x) { return (float)exp((double)x); }

// monotonic float->uint key
__device__ __forceinline__ unsigned fkey(float s) {
  unsigned u = __float_as_uint(s);
  return ((int)u < 0) ? ~u : (u | 0x80000000u);
}

// Wave-aggregated LDS histogram add: one atomic per distinct bin per wave.
__device__ __forceinline__ void agg_add(unsigned* h, unsigned bin, bool pred) {
  unsigned long long rem = __ballot(pred);
  const int lane = threadIdx.x & 63;
  while (rem) {
    int leader = __ffsll(rem) - 1;
    unsigned lb = (unsigned)__shfl((int)bin, leader, 64);
    unsigned long long m = __ballot(pred && bin == lb);
    if (lane == leader) atomicAdd(&h[lb], (unsigned)__popcll(m));
    rem &= ~m;
  }
}

// 4 lanes per anchor; argmax on raw logits; one exact sigmoid per anchor;
// fused per-block LDS histogram of key[31:20] merged to ghist1 (nonzero bins only).
__launch_bounds__(1024)
__global__ void k_score(const float* __restrict__ cls, float* __restrict__ scores,
                        int* __restrict__ labels, unsigned* __restrict__ ghist1, int M) {
  __shared__ unsigned h1[4096];
  const int t = threadIdx.x;
  #pragma unroll
  for (int k = 0; k < 4; ++k) h1[t + 1024 * k] = 0u;
  __syncthreads();

  int gid = blockIdx.x * 1024 + t;
  int anchor = gid >> 2;
  int q = gid & 3;
  bool act = anchor < M;
  float lv[20];
  float best = -3.4e38f; int bc = 0;
  if (act) {
    const float4* row = reinterpret_cast<const float4*>(cls) + (size_t)anchor * (NCLS / 4);
    #pragma unroll
    for (int k = 0; k < 5; ++k) {
      float4 v = row[q + 4 * k];
      int cbase = (q + 4 * k) * 4;
      lv[4 * k + 0] = v.x; lv[4 * k + 1] = v.y; lv[4 * k + 2] = v.z; lv[4 * k + 3] = v.w;
      if (v.x > best) { best = v.x; bc = cbase + 0; }
      if (v.y > best) { best = v.y; bc = cbase + 1; }
      if (v.z > best) { best = v.z; bc = cbase + 2; }
      if (v.w > best) { best = v.w; bc = cbase + 3; }
    }
  } else {
    #pragma unroll
    for (int k = 0; k < 20; ++k) lv[k] = -3.4e38f;
  }
  #pragma unroll
  for (int d = 1; d < 4; d <<= 1) {
    float ob = __shfl_xor(best, d, 64);
    int oc = __shfl_xor(bc, d, 64);
    if (ob > best || (ob == best && oc < bc)) { best = ob; bc = oc; }
  }
  float s = sigmoid_np(best);
  // collision band: logit gap below this can round to the same float sigmoid
  float sp = s * (1.0f - s);
  float band = (s < 1.0f && sp > 0.0f) ? (4.8e-7f / sp) : 3.4e38f;  // 8 ulps margin
  float thresh = best - band;
  int cclose = 1 << 30;
  #pragma unroll
  for (int k = 0; k < 5; ++k) {
    #pragma unroll
    for (int j = 0; j < 4; ++j) {
      int c = (q + 4 * k) * 4 + j;
      if (lv[4 * k + j] >= thresh && c < cclose) cclose = c;
    }
  }
  #pragma unroll
  for (int d = 1; d < 4; d <<= 1) {
    int oc = __shfl_xor(cclose, d, 64);
    if (oc < cclose) cclose = oc;
  }
  int lab = bc;
  if (act && cclose < bc && q == 0) {  // rare: exact serial argmax over rounded sigmoids
    float bp = -1.0f; int bl = 0;
    for (int c = 0; c < NCLS; ++c) {
      float p = sigmoid_np(cls[(size_t)anchor * NCLS + c]);
      if (p > bp) { bp = p; bl = c; }
    }
    lab = bl;
  }
  if (act && q == 0) {
    scores[anchor] = s;
    labels[anchor] = lab;
  }
  agg_add(h1, fkey(s) >> 20, act && q == 0);
  __syncthreads();
  #pragma unroll
  for (int k = 0; k < 4; ++k) {
    unsigned c = h1[t + 1024 * k];
    if (c) atomicAdd(&ghist1[t + 1024 * k], c);
  }
}

// Each block recomputes B1 (coarse threshold bin) from ghist1, then histograms
// key bits [19:8] of elements in bin B1 into global ghist2. Block 0 stores meta.
__launch_bounds__(1024)
__global__ void k_hist2(const unsigned* __restrict__ ghist1, const float* __restrict__ scores,
                        unsigned* __restrict__ ghist2, unsigned* __restrict__ gmeta, int M) {
  __shared__ unsigned chunks[1024];
  __shared__ int sB1; __shared__ unsigned sAb;
  const int t = threadIdx.x;
  unsigned hb0 = ghist1[4 * t], hb1 = ghist1[4 * t + 1],
           hb2 = ghist1[4 * t + 2], hb3 = ghist1[4 * t + 3];
  chunks[t] = hb0 + hb1 + hb2 + hb3;
  __syncthreads();
  for (int d = 1; d < 1024; d <<= 1) {   // inclusive suffix sum
    unsigned v = chunks[t] + ((t + d < 1024) ? chunks[t + d] : 0u);
    __syncthreads();
    chunks[t] = v;
    __syncthreads();
  }
  {
    unsigned ssc = chunks[t];
    unsigned ssn = (t + 1 < 1024) ? chunks[t + 1] : 0u;
    if (ssc >= (unsigned)TOPK && ssn < (unsigned)TOPK) {
      unsigned hb[4] = {hb0, hb1, hb2, hb3};
      unsigned run = ssn;
      for (int b = 3; b >= 0; --b) {
        run += hb[b];
        if (run >= (unsigned)TOPK) { sB1 = 4 * t + b; sAb = run - hb[b]; break; }
      }
    }
  }
  __syncthreads();
  const unsigned B1 = (unsigned)sB1;
  if (blockIdx.x == 0 && t == 0) { gmeta[0] = B1; gmeta[1] = sAb; }

  int base = (blockIdx.x * 1024 + t) * 4;
  if (base + 3 < M) {
    float4 v = *reinterpret_cast<const float4*>(scores + base);
    unsigned k0 = fkey(v.x), k1 = fkey(v.y), k2 = fkey(v.z), k3 = fkey(v.w);
    if ((k0 >> 20) == B1) atomicAdd(&ghist2[(k0 >> 8) & 0xFFFu], 1u);
    if ((k1 >> 20) == B1) atomicAdd(&ghist2[(k1 >> 8) & 0xFFFu], 1u);
    if ((k2 >> 20) == B1) atomicAdd(&ghist2[(k2 >> 8) & 0xFFFu], 1u);
    if ((k3 >> 20) == B1) atomicAdd(&ghist2[(k3 >> 8) & 0xFFFu], 1u);
  } else {
    for (int j = base; j < M; ++j) {
      unsigned k0 = fkey(scores[j]);
      if ((k0 >> 20) == B1) atomicAdd(&ghist2[(k0 >> 8) & 0xFFFu], 1u);
    }
  }
}

// Each block recomputes the 24-bit threshold T from ghist2+meta, then compacts
// its slice of keys >= T into the global candidate buffer (1 atomic per block).
__launch_bounds__(1024)
__global__ void k_compact(const unsigned* __restrict__ ghist2, const unsigned* __restrict__ gmeta,
                          const float* __restrict__ scores,
                          unsigned long long* __restrict__ cand, unsigned* __restrict__ gcount,
                          int M) {
  __shared__ unsigned chunks[1024];
  __shared__ int sB2;
  __shared__ unsigned wcnt[16];
  __shared__ unsigned sbase;
  const int t = threadIdx.x;
  const unsigned B1 = gmeta[0], nAb = gmeta[1];
  unsigned hb0 = ghist2[4 * t], hb1 = ghist2[4 * t + 1],
           hb2 = ghist2[4 * t + 2], hb3 = ghist2[4 * t + 3];
  chunks[t] = hb0 + hb1 + hb2 + hb3;
  __syncthreads();
  for (int d = 1; d < 1024; d <<= 1) {
    unsigned v = chunks[t] + ((t + d < 1024) ? chunks[t + d] : 0u);
    __syncthreads();
    chunks[t] = v;
    __syncthreads();
  }
  {
    unsigned ssc = nAb + chunks[t];
    unsigned ssn = nAb + ((t + 1 < 1024) ? chunks[t + 1] : 0u);
    if (ssc >= (unsigned)TOPK && ssn < (unsigned)TOPK) {
      unsigned hb[4] = {hb0, hb1, hb2, hb3};
      unsigned run = ssn;
      for (int b = 3; b >= 0; --b) {
        run += hb[b];
        if (run >= (unsigned)TOPK) { sB2 = 4 * t + b; break; }
      }
    }
  }
  __syncthreads();
  const unsigned T = (B1 << 20) | ((unsigned)sB2 << 8);

  int base = (blockIdx.x * 1024 + t) * 4;
  unsigned keys[4]; int idxs[4]; int np = 0;
  #pragma unroll
  for (int j = 0; j < 4; ++j) {
    int i = base + j;
    if (i < M) {
      unsigned key = fkey(scores[i]);
      if (key >= T) { keys[np] = key; idxs[np] = i; ++np; }
    }
  }
  // wave inclusive scan of np
  const int lane = t & 63, wid = t >> 6;
  int sc = np;
  #pragma unroll
  for (int d = 1; d < 64; d <<= 1) {
    int o = __shfl_up(sc, d, 64);
    if (lane >= d) sc += o;
  }
  if (lane == 63) wcnt[wid] = (unsigned)sc;
  __syncthreads();
  if (t == 0) {
    unsigned acc = 0;
    for (int w = 0; w < 16; ++w) { unsigned v = wcnt[w]; wcnt[w] = acc; acc += v; }
    sbase = acc ? atomicAdd(gcount, acc) : 0u;
  }
  __syncthreads();
  unsigned pos = sbase + wcnt[wid] + (unsigned)(sc - np);
  for (int j = 0; j < np; ++j) {
    if (pos < (unsigned)CAND_CAP)
      cand[pos] = ((unsigned long long)keys[j] << 32) | (unsigned)(~(unsigned)idxs[j]);
    ++pos;
  }
}

// Exact rank (N^2 over <=CAND_CAP distinct keys) + decode, one block.
__launch_bounds__(1024)
__global__ void k_rank(const unsigned long long* __restrict__ cand, const unsigned* __restrict__ gcount,
                       const int* __restrict__ labels, const float* __restrict__ reg,
                       const float* __restrict__ asz, const int* __restrict__ pW, int A,
                       float* __restrict__ sel_score, int* __restrict__ sel_label,
                       float* __restrict__ boxes, float* __restrict__ areas,
                       float* __restrict__ obox) {
  __shared__ unsigned long long ck[CAND_CAP];  // 32KB
  const int t = threadIdx.x;
  unsigned n = *gcount; if (n > (unsigned)CAND_CAP) n = (unsigned)CAND_CAP;
  for (int i = t; i < CAND_CAP; i += 1024) ck[i] = (i < (int)n) ? cand[i] : 0ull;
  __syncthreads();
  for (int c = t; c < (int)n; c += 1024) {
    unsigned long long my = ck[c];
    int r = 0;
    for (int j = 0; j < (int)n; ++j) r += (ck[j] > my);   // uniform j: LDS broadcast
    if (r < TOPK) {
      unsigned key = (unsigned)(my >> 32);
      unsigned u = (key & 0x80000000u) ? (key ^ 0x80000000u) : ~key;
      float scv = __uint_as_float(u);
      int idx = (int)(~(unsigned)my);
      int lab = labels[idx];
      int W = *pW;
      int a = idx % A;
      int cell = idx / A;
      int x = cell % W;
      int y = cell / W;
      float aw = asz[a * 2 + 0], ah = asz[a * 2 + 1];
      float ax = ((float)x + 0.5f) * 32.0f;
      float ay = ((float)y + 0.5f) * 32.0f;
      float4 rg = *reinterpret_cast<const float4*>(reg + (size_t)idx * 4);
      float offx = fminf(fmaxf(rg.x * aw, -32.0f), 32.0f);
      float offy = fminf(fmaxf(rg.y * ah, -32.0f), 32.0f);
      float cx = ax + offx, cy = ay + offy;
      const float SC = 4.135166556742356f;  // log(1000/16)
      float bw = aw * exp_np(fminf(rg.z, SC));
      float bh = ah * exp_np(fminf(rg.w, SC));
      float x1 = cx - 0.5f * bw, y1 = cy - 0.5f * bh;
      float x2 = cx + 0.5f * bw, y2 = cy + 0.5f * bh;
      float off = (float)lab * 100000.0f;
      float ox1 = x1 + off, oy1 = y1 + off, ox2 = x2 + off, oy2 = y2 + off;
      sel_score[r] = scv; sel_label[r] = lab;
      boxes[r * 4 + 0] = x1; boxes[r * 4 + 1] = y1;
      boxes[r * 4 + 2] = x2; boxes[r * 4 + 3] = y2;
      obox[0 * 1024 + r] = ox1; obox[1 * 1024 + r] = oy1;
      obox[2 * 1024 + r] = ox2; obox[3 * 1024 + r] = oy2;
      areas[r] = (ox2 - ox1) * (oy2 - oy1);  // areas on offset boxes, like the reference
    }
  }
}

// COLUMN-form mask: maskC[c*1024 + j] = u64 whose bit i says
// "box c*64+i suppresses box j" (IoU > thr, c*64+i < j). IoU is symmetric,
// so this is the old row-mask computation with i/j roles swapped.
// c is block-uniform (256 | 1024); inner i loop is block-uniform -> LDS broadcast.
__launch_bounds__(256)
__global__ void k_mask(const float* __restrict__ obox, const float* __restrict__ areas,
                       unsigned long long* __restrict__ maskC) {
  __shared__ float so0[1024], so1[1024], so2[1024], so3[1024], sa[1024];
  const int t = threadIdx.x;
  int g = blockIdx.x * 256 + t;
  int c = g >> 10, j = g & 1023;
  for (int idx = t; idx < 1024; idx += 256) {
    so0[idx] = obox[idx];        so1[idx] = obox[1024 + idx];
    so2[idx] = obox[2048 + idx]; so3[idx] = obox[3072 + idx];
    sa[idx] = areas[idx];
  }
  __syncthreads();
  if (j >= TOPK) { maskC[c * 1024 + j] = 0ull; return; }
  float x1j = so0[j], y1j = so1[j], x2j = so2[j], y2j = so3[j];
  float aj = sa[j];
  unsigned long long bits = 0ull;
  int i0 = c * 64;
  for (int ii = 0; ii < 64; ++ii) {
    int i = i0 + ii;                       // block-uniform: LDS broadcast
    if (i < TOPK && i < j) {
      float xx1 = fmaxf(so0[i], x1j);
      float yy1 = fmaxf(so1[i], y1j);
      float xx2 = fminf(so2[i], x2j);
      float yy2 = fminf(so3[i], y2j);
      float inter = fmaxf(1e-28f, xx2 - xx1) * fmaxf(1e-28f, yy2 - yy1);
      float uni = sa[i] + aj - inter + 1e-14f;
      float iou = inter / uni;             // IEEE division: bit-matches reference
      if (iou > 0.6f) bits |= (1ull << ii);
    }
  }
  maskC[c * 1024 + j] = bits;
}

// 8-WAVE staging + single-wave greedy NMS + 8-wave epilogue.
// R8 lesson: a lone wave serializes every global load (~900cy each, ~80us).
// Here 8 waves stage the 68KB mask triangle + scores into LDS in parallel
// (loads pipeline within AND across waves), wave 0 runs the greedy from LDS,
// and all 8 waves write the outputs. Greedy has a non-suppressor fast path:
// boxes that suppress nobody are kept en masse (no per-box ballot).
__launch_bounds__(512, 1)
__global__ void k_nms(const unsigned long long* __restrict__ maskC,
                      const float* __restrict__ sel_score, const int* __restrict__ sel_label,
                      const float* __restrict__ boxes,
                      const int* __restrict__ pW, const int* __restrict__ pH,
                      float* __restrict__ out) {
  __shared__ unsigned long long sm[16 * 16 * 64];   // 128KB, upper triangle used
  __shared__ float ssc[1024];                       // 4KB staged scores
  __shared__ unsigned long long kwS[16];
  const int tid = threadIdx.x;
  const int wv = tid >> 6, lane = tid & 63;

  {  // stage mask triangle: 136 (f,g) pairs distributed over 8 waves
    int pair = 0;
    #pragma unroll
    for (int f = 0; f < 16; ++f) {
      #pragma unroll
      for (int g = f; g < 16; ++g) {
        if ((pair & 7) == wv)
          sm[(f * 16 + g) * 64 + lane] = maskC[f * 1024 + g * 64 + lane];
        ++pair;
      }
    }
  }
  for (int i = tid; i < 1024; i += 512)
    ssc[i] = (i < TOPK) ? sel_score[i] : 0.0f;
  __syncthreads();

  if (tid < 64) {  // wave 0: greedy, fully out of LDS/registers
    unsigned long long supp[16];
    #pragma unroll
    for (int f = 0; f < 16; ++f) supp[f] = 0ull;
    #pragma unroll
    for (int f = 0; f < 16; ++f) {
      unsigned long long ct = sm[(f * 16 + f) * 64 + lane];
      unsigned long long w[16];            // cross words prefetched (static idx)
      #pragma unroll
      for (int g = f + 1; g < 16; ++g) w[g] = sm[(f * 16 + g) * 64 + lane];
      int r = f * 64 + lane;
      unsigned long long valid = __ballot((r < TOPK) && (ssc[r] >= 0.05f));
      unsigned long long sup_any = __ballot(ct != 0ull);
      unsigned long long avail = valid & ~supp[f];
      unsigned long long kwf = 0ull;
      while (avail) {
        unsigned long long fs = avail & sup_any;
        if (!fs) { kwf |= avail; break; }      // rest suppress nobody: keep all
        int i = __ffsll((long long)fs) - 1;
        unsigned long long below = (1ull << i) - 1ull;
        kwf |= avail & below;                  // non-suppressors before i: keep
        kwf |= (1ull << i);                    // keep box i
        unsigned long long vict = __ballot(((ct >> i) & 1ull) != 0ull);
        avail &= ~vict;
        avail &= ~(below | (1ull << i));
      }
      if (lane == 0) kwS[f] = kwf;
      #pragma unroll
      for (int g = f + 1; g < 16; ++g)
        supp[g] |= __ballot((w[g] & kwf) != 0ull);
    }
  }
  __syncthreads();

  // epilogue: 8 waves in parallel, 2 rows per thread
  float sw = (float)(*pW * 32);
  float sh = (float)(*pH * 32);
  const float4* b4 = reinterpret_cast<const float4*>(boxes);
  for (int r = tid; r < TOPK; r += 512) {
    bool kp = (kwS[r >> 6] >> (r & 63)) & 1ull;
    float m = kp ? 1.0f : 0.0f;
    float4 b = b4[r];
    float b0 = fminf(fmaxf(b.x / sw, 0.0f), 1.0f) * m;
    float b1 = fminf(fmaxf(b.y / sh, 0.0f), 1.0f) * m;
    float b2 = fminf(fmaxf(b.z / sw, 0.0f), 1.0f) * m;
    float b3 = fminf(fmaxf(b.w / sh, 0.0f), 1.0f) * m;
    out[r * 4 + 0] = b0; out[r * 4 + 1] = b1;
    out[r * 4 + 2] = b2; out[r * 4 + 3] = b3;
    out[TOPK * 4 + r] = ssc[r] * m;
    out[TOPK * 5 + r] = kp ? (float)sel_label[r] : -1.0f;
    out[TOPK * 6 + r] = m;
  }
}

extern "C" void kernel_launch(void* const* d_in, const int* in_sizes, int n_in,
                              void* d_out, int out_size, void* d_ws, size_t ws_size,
                              hipStream_t stream) {
  const float* cls = (const float*)d_in[0];
  const float* reg = (const float*)d_in[1];
  const float* asz = (const float*)d_in[2];
  const int* pH = (const int*)d_in[3];
  const int* pW = (const int*)d_in[4];
  int M = in_sizes[0] / NCLS;
  int A = in_sizes[2] / 2;

  char* ws = (char*)d_ws;
  size_t off = 0;
  auto alloc = [&](size_t bytes) { size_t o = off; off = (off + bytes + 255) & ~(size_t)255; return o; };
  size_t o_h1    = alloc(4096 * sizeof(unsigned));
  size_t o_h2    = alloc(4096 * sizeof(unsigned));
  size_t o_misc  = alloc(256);                       // gcount @ +0, gmeta @ +8
  size_t zero_end = off;
  size_t o_cand  = alloc((size_t)CAND_CAP * sizeof(unsigned long long));
  size_t o_sc    = alloc((size_t)M * sizeof(float));
  size_t o_lb    = alloc((size_t)M * sizeof(int));
  size_t o_ssc   = alloc(1024 * sizeof(float));
  size_t o_slb   = alloc(1024 * sizeof(int));
  size_t o_box   = alloc((size_t)TOPK * 4 * sizeof(float));
  size_t o_area  = alloc(1024 * sizeof(float));
  size_t o_obox  = alloc(4 * 1024 * sizeof(float));
  size_t o_mask  = alloc((size_t)NWORDS * 1024 * sizeof(unsigned long long));
  (void)ws_size; (void)out_size; (void)n_in;

  hipMemsetAsync(ws, 0, zero_end, stream);   // ghist1 + ghist2 + gcount/gmeta

  int nblk_score = (M * 4 + 1023) / 1024;
  k_score<<<nblk_score, 1024, 0, stream>>>(
      cls, (float*)(ws + o_sc), (int*)(ws + o_lb), (unsigned*)(ws + o_h1), M);

  int nblk_scan = ((M + 3) / 4 + 1023) / 1024;
  k_hist2<<<nblk_scan, 1024, 0, stream>>>(
      (const unsigned*)(ws + o_h1), (const float*)(ws + o_sc),
      (unsigned*)(ws + o_h2), (unsigned*)(ws + o_misc + 8), M);
  k_compact<<<nblk_scan, 1024, 0, stream>>>(
      (const unsigned*)(ws + o_h2), (const unsigned*)(ws + o_misc + 8),
      (const float*)(ws + o_sc),
      (unsigned long long*)(ws + o_cand), (unsigned*)(ws + o_misc), M);
  k_rank<<<1, 1024, 0, stream>>>(
      (const unsigned long long*)(ws + o_cand), (const unsigned*)(ws + o_misc),
      (const int*)(ws + o_lb), reg, asz, pW, A,
      (float*)(ws + o_ssc), (int*)(ws + o_slb),
      (float*)(ws + o_box), (float*)(ws + o_area), (float*)(ws + o_obox));
  k_mask<<<(NWORDS * 1024) / 256, 256, 0, stream>>>(
      (const float*)(ws + o_obox), (const float*)(ws + o_area),
      (unsigned long long*)(ws + o_mask));
  k_nms<<<1, 512, 0, stream>>>(
      (const unsigned long long*)(ws + o_mask),
      (const float*)(ws + o_ssc), (const int*)(ws + o_slb),
      (const float*)(ws + o_box), pW, pH, (float*)d_out);
}